// Round 1
// baseline (194.701 us; speedup 1.0000x reference)
//
#include <hip/hip_runtime.h>
#include <hip/hip_bf16.h>
#include <hip/hip_cooperative_groups.h>

namespace cg = cooperative_groups;

#define BB 8
#define NN 256
#define DD 128
#define HH 512
#define EPSV 1e-5f
#define TPB 16
#define BPL (NN/TPB)        // 16 pool partials per batch
#define GRID ((BB*NN)/TPB)  // 128 blocks

typedef unsigned short ushort_t;
typedef __attribute__((ext_vector_type(8))) short bf16x8;
typedef __attribute__((ext_vector_type(4))) float f32x4;

// converted-weight segment sizes (bf16 elements)
#define WPSZ (256*128)           // 32768
#define W1SZ (128*512)           // 65536
#define W2SZ (512*128)           // 65536
#define LAYSZ (WPSZ+W1SZ+W2SZ)   // 163840
#define TOTW (2*LAYSZ)           // 327680  == 5 * GRID * 512

__device__ __forceinline__ ushort_t f2b(float v){
  __hip_bfloat16 h = __float2bfloat16(v);
  return *(ushort_t*)&h;
}

__device__ __forceinline__ void waveRed2(float &a, float &b){
  #pragma unroll
  for (int off=32; off>=1; off>>=1){
    a += __shfl_xor(a, off, 64);
    b += __shfl_xor(b, off, 64);
  }
}

__device__ __forceinline__ void poolMerge(float &m1, float &m2, int &am,
                                          float o1, float o2, int oa){
  if (o1 > m1){ m2 = fmaxf(m1, o2); m1 = o1; am = oa; }
  else        { m2 = fmaxf(m2, o1); }
}

// Single cooperative kernel, 128 blocks x 512 threads (16 tokens/block).
// Phase 0: closed-form embed (LN stats affine in x -> 9 scalars), in-block
//   full-batch pool scan, AND grid-cooperative conversion of ALL weights
//   (both layers) from f32 [K][N] to bf16 fragment-ordered records in ws.
// grid.sync #1: weights visible -> both layers' GEMMs use coalesced 16B
//   bf16x8 weight loads (no scalar gathers, no per-lane f2b).
// Layer 0 GEMM stack entirely from LDS (h kept resident), writes layer-1
//   pool partials to ws. grid.sync #2. Layer 1 merges partials, GEMM
//   stack, writes final h to d_out.
// LDS A-operand buffers (catb/h1b/ub) are XOR-swizzled (byte ^= (row&7)<<4)
// so ds_read_b128 column-slices are bank-conflict-free.
__global__ __launch_bounds__(512, 2) void k_all(
    const float* __restrict__ x, const float* __restrict__ We,
    const float* __restrict__ be, const float* __restrict__ ge,
    const float* __restrict__ bge,
    float* __restrict__ hio,
    float* __restrict__ pm1, float* __restrict__ pm2, int* __restrict__ pma,
    ushort_t* __restrict__ wcvt,
    const float* __restrict__ Wp, const float* __restrict__ bp,
    const float* __restrict__ gp, const float* __restrict__ bgp,
    const float* __restrict__ W1, const float* __restrict__ b1,
    const float* __restrict__ W2, const float* __restrict__ b2,
    const float* __restrict__ gf, const float* __restrict__ bgf)
{
  cg::grid_group gg = cg::this_grid();

  int tid = threadIdx.x;
  int d = tid & 127, fourth = tid >> 7;
  int wv = tid >> 6;            // wave 0..7
  int lane = tid & 63;
  int m = lane & 15, q = lane >> 4;
  int t0 = blockIdx.x * TPB;
  int b = t0 >> 8;
  int blk = (t0 >> 4) & (BPL-1);
  int n0a = wv*16;

  __shared__ float    hcur[16*128];   // 8K  h for own 16 tokens (resident across layers)
  __shared__ ushort_t catb[16*256];   // 8K  bf16 A-operand, stage A (swizzled)
  __shared__ float    sA[16*128];     // 8K  f32 GEMM out (A, then C)
  __shared__ ushort_t h1b[16*128];    // 4K  bf16 A-operand, stage B (swizzled)
  __shared__ float    h1f[16*128];    // 8K  f32 h1 (stage-C residual)
  __shared__ ushort_t ub[16*512];     // 16K bf16 A-operand, stage C (swizzled)
  __shared__ float fm1[128], fm2[128];
  __shared__ int   fam[128];
  __shared__ float sm1[4][128], sm2[4][128];
  __shared__ int   sam[4][128];
  __shared__ float xs[512];
  __shared__ float red9[2][12];
  __shared__ float stats[12];

  // ---- stage x for the whole batch (256 tokens x 2) ----
  xs[tid] = x[(size_t)b*512 + tid];

  // ---- one-time cooperative weight conversion: f32 [K][N] -> bf16 records.
  // Record layout per GEMM tile: off = rec*512 + lane*8 + j, where
  // rec = n0tile*(K/32)+ks, element = W[ks*32 + (lane>>4)*8 + j][n0tile*16 + (lane&15)].
  {
    int e = blockIdx.x*512 + tid;
    #pragma unroll
    for (int it=0; it<5; ++it){
      int l2 = (e >= LAYSZ) ? 1 : 0;
      int el = e - l2*LAYSZ;
      const float* src; int N, KSlog, off;
      if (el < WPSZ)           { src = Wp + (size_t)l2*WPSZ; N = 128; KSlog = 3; off = el; }
      else if (el < WPSZ+W1SZ) { src = W1 + (size_t)l2*W1SZ; N = 512; KSlog = 2; off = el - WPSZ; }
      else                     { src = W2 + (size_t)l2*W2SZ; N = 128; KSlog = 4; off = el - (WPSZ+W1SZ); }
      int rec = off >> 9;
      int ln  = (off >> 3) & 63;
      int j   = off & 7;
      int n0t = rec >> KSlog;
      int ks  = rec & ((1<<KSlog)-1);
      int row = ks*32 + ((ln>>4)<<3) + j;
      int col = (n0t<<4) + (ln&15);
      wcvt[e] = f2b(src[(size_t)row*N + col]);
      e += GRID*512;
    }
  }

  // ---- 9 reduction scalars of (We,be) over d ----
  float a = We[d], bw = We[128+d], c = be[d];
  if (fourth == 0){
    float r0=a, r1=bw;        waveRed2(r0,r1);
    float r2=c, r3=a*a;       waveRed2(r2,r3);
    float r4=bw*bw, r5=c*c;   waveRed2(r4,r5);
    float r6=a*bw, r7=a*c;    waveRed2(r6,r7);
    float r8=bw*c, r9=0.f;    waveRed2(r8,r9);
    int w = (tid >> 6) & 1;
    if (lane == 0){
      red9[w][0]=r0; red9[w][1]=r1; red9[w][2]=r2; red9[w][3]=r3;
      red9[w][4]=r4; red9[w][5]=r5; red9[w][6]=r6; red9[w][7]=r7;
      red9[w][8]=r8;
    }
  }
  __syncthreads();
  if (tid < 9) stats[tid] = (red9[0][tid] + red9[1][tid]) * (1.f/128);
  __syncthreads();
  {
    float mA=stats[0], mB=stats[1], mC=stats[2];
    float SAA=stats[3], SBB=stats[4], SCC=stats[5];
    float SAB=stats[6], SAC=stats[7], SBC=stats[8];
    float gev = ge[d], bgev = bge[d];
    // ---- full-batch pool scan: fourth f covers tokens f*64..f*64+63 ----
    float m1=-3.4e38f, m2=-3.4e38f; int am=0;
    for (int i=0;i<64;++i){
      int n = fourth*64 + i;
      float x0 = xs[2*n], x1 = xs[2*n+1];
      float v    = fmaf(x0, a,  fmaf(x1, bw, c));
      float mean = fmaf(x0, mA, fmaf(x1, mB, mC));
      float ev2  = x0*x0*SAA + x1*x1*SBB + SCC
                 + 2.f*(x0*x1*SAB + x0*SAC + x1*SBC);
      float var = ev2 - mean*mean;
      float hv = (v-mean)*rsqrtf(var+EPSV)*gev + bgev;
      poolMerge(m1,m2,am, hv, -3.4e38f, n);
    }
    sm1[fourth][d]=m1; sm2[fourth][d]=m2; sam[fourth][d]=am;
    // ---- own 16 tokens' h0 ----
    #pragma unroll
    for (int rep=0; rep<4; ++rep){
      int t = fourth*4 + rep;
      int n = (t0 & 255) + t;
      float x0 = xs[2*n], x1 = xs[2*n+1];
      float v    = fmaf(x0, a,  fmaf(x1, bw, c));
      float mean = fmaf(x0, mA, fmaf(x1, mB, mC));
      float ev2  = x0*x0*SAA + x1*x1*SBB + SCC
                 + 2.f*(x0*x1*SAB + x0*SAC + x1*SBC);
      float var = ev2 - mean*mean;
      hcur[t*128 + d] = (v-mean)*rsqrtf(var+EPSV)*gev + bgev;
    }
  }

  // weights + own h + layer-0 pool partials (in sm) all staged
  __threadfence();
  gg.sync();

  for (int layer=0; layer<2; ++layer){
    const float* bpL  = bp  + layer*DD;
    const float* gpL  = gp  + layer*DD;
    const float* bgpL = bgp + layer*DD;
    const float* b1L  = b1  + layer*HH;
    const float* b2L  = b2  + layer*DD;
    const float* gfL  = gf  + layer*DD;
    const float* bgfL = bgf + layer*DD;
    const ushort_t* wAb = wcvt + (size_t)layer*LAYSZ;
    const ushort_t* wBb = wAb + WPSZ;
    const ushort_t* wCb = wAb + WPSZ + W1SZ;

    if (layer == 1){
      // merge the batch's 16 layer-0 pool partials (4 per fourth)
      size_t base = ((size_t)b*BPL + fourth*4)*128 + d;
      float m1 = pm1[base], m2 = pm2[base]; int am = pma[base];
      #pragma unroll
      for (int i=1;i<4;++i)
        poolMerge(m1,m2,am, pm1[base+(size_t)i*128], pm2[base+(size_t)i*128],
                  pma[base+(size_t)i*128]);
      sm1[fourth][d]=m1; sm2[fourth][d]=m2; sam[fourth][d]=am;
      __syncthreads();
    }
    if (fourth==0){
      float m1=sm1[0][d], m2=sm2[0][d]; int am=sam[0][d];
      #pragma unroll
      for (int p=1;p<4;++p) poolMerge(m1,m2,am, sm1[p][d], sm2[p][d], sam[p][d]);
      fm1[d]=m1; fm2[d]=m2; fam[d]=am;
    }
    __syncthreads();

    // ---- cat build: catb[16][256] bf16 from hcur + pooled (swizzled) ----
    #pragma unroll
    for (int rep=0; rep<8; ++rep){
      int e = rep*512 + tid;
      int t = e >> 8, cc = e & 255;
      int n = (t0 & 255) + t;
      float v;
      if (cc < DD) v = hcur[t*128 + cc];
      else { int c2 = cc - DD; v = (n==fam[c2]) ? fm2[c2] : fm1[c2]; }
      *(ushort_t*)((char*)catb + ((e*2) ^ ((t&7)<<4))) = f2b(v);
    }
    __syncthreads();

    // ---- stage A: [16x128] = cat[16x256] @ Wp ----
    {
      f32x4 acc = {0.f,0.f,0.f,0.f};
      const char* apb = (const char*)catb;
      int abase = (m*256 + q*8)*2;
      int sw = (m&7)<<4;
      #pragma unroll
      for (int ks=0; ks<8; ++ks){
        bf16x8 wf = *(const bf16x8*)(wAb + ((size_t)(wv*8+ks)*64 + lane)*8);
        bf16x8 af = *(const bf16x8*)(apb + ((abase + ks*64) ^ sw));
        acc = __builtin_amdgcn_mfma_f32_16x16x32_bf16(af, wf, acc, 0,0,0);
      }
      #pragma unroll
      for (int r=0;r<4;++r) sA[(q*4+r)*128 + n0a + m] = acc[r];
    }
    __syncthreads();

    // ---- LN-A: wave wv handles tokens wv and wv+8; lane g -> d=2g,2g+1 ----
    #pragma unroll
    for (int rep=0; rep<2; ++rep){
      int t = rep*8 + wv, g = lane;
      float2 v2 = *(const float2*)&sA[t*128 + 2*g];
      float v0 = v2.x + bpL[2*g]   + hcur[t*128 + 2*g];
      float v1 = v2.y + bpL[2*g+1] + hcur[t*128 + 2*g + 1];
      float s = v0+v1, qq = v0*v0 + v1*v1;
      waveRed2(s,qq);
      float mean = s*(1.f/128), var = qq*(1.f/128) - mean*mean;
      float rs = rsqrtf(var + EPSV);
      float o0 = (v0-mean)*rs*gpL[2*g]   + bgpL[2*g];
      float o1 = (v1-mean)*rs*gpL[2*g+1] + bgpL[2*g+1];
      unsigned pk = (unsigned)f2b(o0) | ((unsigned)f2b(o1) << 16);
      *(unsigned*)((char*)h1b + (((t*128 + 2*g)*2) ^ ((t&7)<<4))) = pk;
      *(float2*)&h1f[t*128 + 2*g] = make_float2(o0, o1);
    }
    __syncthreads();

    // ---- stage B: [16x512] = h1[16x128] @ W1 ----
    {
      const char* apb = (const char*)h1b;
      int abase = (m*128 + q*8)*2;
      int sw = (m&7)<<4;
      bf16x8 af[4];
      #pragma unroll
      for (int ks=0; ks<4; ++ks)
        af[ks] = *(const bf16x8*)(apb + ((abase + ks*64) ^ sw));
      #pragma unroll
      for (int half=0; half<2; ++half){
        #pragma unroll
        for (int i=0;i<2;++i){
          int n0 = (half*2+i)*128 + wv*16;
          int n0t = (half*2+i)*8 + wv;
          f32x4 acc = {0.f,0.f,0.f,0.f};
          #pragma unroll
          for (int ks=0; ks<4; ++ks){
            bf16x8 wf = *(const bf16x8*)(wBb + ((size_t)(n0t*4+ks)*64 + lane)*8);
            acc = __builtin_amdgcn_mfma_f32_16x16x32_bf16(af[ks], wf, acc, 0,0,0);
          }
          float bb = b1L[n0+m];
          #pragma unroll
          for (int r=0;r<4;++r){
            int row = q*4+r;
            *(ushort_t*)((char*)ub + (((row*512 + n0 + m)*2) ^ ((row&7)<<4)))
                = f2b(fmaxf(acc[r] + bb, 0.f));
          }
        }
      }
    }
    __syncthreads();

    // ---- stage C: [16x128] = u[16x512] @ W2 ----
    {
      f32x4 acc = {0.f,0.f,0.f,0.f};
      const char* apb = (const char*)ub;
      int abase = (m*512 + q*8)*2;
      int sw = (m&7)<<4;
      #pragma unroll
      for (int kk=0; kk<16; ++kk){
        bf16x8 wf = *(const bf16x8*)(wCb + ((size_t)(wv*16+kk)*64 + lane)*8);
        bf16x8 af = *(const bf16x8*)(apb + ((abase + kk*64) ^ sw));
        acc = __builtin_amdgcn_mfma_f32_16x16x32_bf16(af, wf, acc, 0,0,0);
      }
      #pragma unroll
      for (int r=0;r<4;++r) sA[(q*4+r)*128 + n0a + m] = acc[r];
    }
    __syncthreads();

    // ---- LN-C: residual h1f; layer0 -> hcur (+pool partials), layer1 -> out ----
    #pragma unroll
    for (int rep=0; rep<2; ++rep){
      int t = rep*8 + wv, g = lane;
      float2 v2 = *(const float2*)&sA[t*128 + 2*g];
      float v0 = v2.x + b2L[2*g]   + h1f[t*128 + 2*g];
      float v1 = v2.y + b2L[2*g+1] + h1f[t*128 + 2*g + 1];
      float s = v0+v1, qq = v0*v0 + v1*v1;
      waveRed2(s,qq);
      float mean = s*(1.f/128), var = qq*(1.f/128) - mean*mean;
      float rs = rsqrtf(var + EPSV);
      float o0 = (v0-mean)*rs*gfL[2*g]   + bgfL[2*g];
      float o1 = (v1-mean)*rs*gfL[2*g+1] + bgfL[2*g+1];
      if (layer == 0) *(float2*)&hcur[t*128 + 2*g] = make_float2(o0, o1);
      else *(float2*)&hio[(size_t)(t0+t)*DD + 2*g] = make_float2(o0, o1);
    }

    if (layer == 0){
      __syncthreads();
      if (tid < 128){
        int nb = t0 & 255;
        float m1 = hcur[tid], m2 = -3.4e38f; int am = nb;
        #pragma unroll
        for (int p=1;p<TPB;++p)
          poolMerge(m1,m2,am, hcur[p*128+tid], -3.4e38f, nb+p);
        size_t idx = ((size_t)b*BPL + blk)*128 + tid;
        pm1[idx]=m1; pm2[idx]=m2; pma[idx]=am;
      }
      __threadfence();
      gg.sync();
    }
  }
}

extern "C" void kernel_launch(void* const* d_in, const int* in_sizes, int n_in,
                              void* d_out, int out_size, void* d_ws, size_t ws_size,
                              hipStream_t stream)
{
  const float* x   = (const float*)d_in[0];
  const float* We  = (const float*)d_in[1];
  const float* be  = (const float*)d_in[2];
  const float* ge  = (const float*)d_in[3];
  const float* bge = (const float*)d_in[4];
  const float* Wp  = (const float*)d_in[5];
  const float* bp  = (const float*)d_in[6];
  const float* gp  = (const float*)d_in[7];
  const float* bgp = (const float*)d_in[8];
  const float* W1  = (const float*)d_in[9];
  const float* b1  = (const float*)d_in[10];
  const float* W2  = (const float*)d_in[11];
  const float* b2  = (const float*)d_in[12];
  const float* gf  = (const float*)d_in[13];
  const float* bgf = (const float*)d_in[14];

  float* hio = (float*)d_out;
  char* ws = (char*)d_ws;
  const size_t NP = (size_t)BB*BPL*128;   // 16384
  float* p1 = (float*)ws;        ws += NP*4;
  float* p2 = (float*)ws;        ws += NP*4;
  int*   pa = (int*)ws;          ws += NP*4;
  ushort_t* wcvt = (ushort_t*)ws;

  void* kargs[] = {
    (void*)&x, (void*)&We, (void*)&be, (void*)&ge, (void*)&bge,
    (void*)&hio, (void*)&p1, (void*)&p2, (void*)&pa, (void*)&wcvt,
    (void*)&Wp, (void*)&bp, (void*)&gp, (void*)&bgp,
    (void*)&W1, (void*)&b1, (void*)&W2, (void*)&b2,
    (void*)&gf, (void*)&bgf
  };
  hipLaunchCooperativeKernel((void*)k_all, dim3(GRID), dim3(512), kargs, 0, stream);
}

// Round 2
// 108.361 us; speedup vs baseline: 1.7968x; 1.7968x over previous
//
#include <hip/hip_runtime.h>
#include <hip/hip_bf16.h>

#define BB 8
#define NN 256
#define DD 128
#define HH 512
#define LL 2
#define EPSV 1e-5f
#define TPB 8            // tokens per block
#define BPL (NN/TPB)     // pool partials per batch = 32

typedef unsigned short ushort_t;
typedef __attribute__((ext_vector_type(8))) short bf16x8;
typedef __attribute__((ext_vector_type(4))) float f32x4;

// converted-weight segment sizes (bf16 elements)
#define WPSZ (256*128)           // 32768
#define W1SZ (128*512)           // 65536
#define W2SZ (512*128)           // 65536
#define LAYSZ (WPSZ+W1SZ+W2SZ)   // 163840
#define TOTW (2*LAYSZ)           // 327680

__device__ __forceinline__ ushort_t f2b(float v){
  __hip_bfloat16 h = __float2bfloat16(v);
  return *(ushort_t*)&h;
}

__device__ __forceinline__ void waveRed2(float &a, float &b){
  #pragma unroll
  for (int off=32; off>=1; off>>=1){
    a += __shfl_xor(a, off, 64);
    b += __shfl_xor(b, off, 64);
  }
}

__device__ __forceinline__ void poolMerge(float &m1, float &m2, int &am,
                                          float o1, float o2, int oa){
  if (o1 > m1){ m2 = fmaxf(m1, o2); m1 = o1; am = oa; }
  else        { m2 = fmaxf(m2, o1); }
}

// One-time weight conversion: f32 [K][N] -> bf16 fragment-ordered records.
// Record layout (per GEMM tile): element off = rec*512 + lane*8 + j holds
// W[ks*32 + (lane>>4)*8 + j][n0tile*16 + (lane&15)], rec = n0tile*(K/32)+ks.
// Each thread packs one bf16x8 chunk (8 rows, one col) -> 16B store.
// A 16-lane group's 8 gathered rows are fully-consumed 64B lines.
__global__ __launch_bounds__(512) void k_prep(
    const float* __restrict__ Wp, const float* __restrict__ W1,
    const float* __restrict__ W2, ushort_t* __restrict__ wcvt)
{
  int e8 = blockIdx.x*512 + threadIdx.x;     // chunk index, 40960 total
  if (e8 >= TOTW/8) return;
  int e = e8*8;
  int l2 = (e >= LAYSZ) ? 1 : 0;
  int el = e - l2*LAYSZ;
  const float* src; int N, KSlog, off;
  if (el < WPSZ)           { src = Wp + (size_t)l2*WPSZ; N = 128; KSlog = 3; off = el; }
  else if (el < WPSZ+W1SZ) { src = W1 + (size_t)l2*W1SZ; N = 512; KSlog = 2; off = el - WPSZ; }
  else                     { src = W2 + (size_t)l2*W2SZ; N = 128; KSlog = 4; off = el - (WPSZ+W1SZ); }
  int rec  = off >> 9;
  int ln   = (off >> 3) & 63;
  int n0t  = rec >> KSlog;
  int ks   = rec & ((1<<KSlog)-1);
  int row0 = ks*32 + ((ln>>4)<<3);
  int col  = (n0t<<4) + (ln&15);
  bf16x8 v;
  #pragma unroll
  for (int j=0;j<8;++j) v[j] = (short)f2b(src[(size_t)(row0+j)*N + col]);
  *(bf16x8*)(wcvt + e) = v;
}

// One kernel per layer, 256 blocks x 512 threads, plain launches (round-0
// verified structure). GEMM weights come from the pre-converted bf16
// fragment records (one coalesced 16B load per MFMA). LDS A-operand
// buffers (catb/h1b/ub) are XOR-swizzled (byte ^= (row&7)<<4) so the
// ds_read_b128 column-slices are bank-conflict-free.
__global__ __launch_bounds__(512, 2) void k_net(
    int layer,
    const float* __restrict__ x, const float* __restrict__ We,
    const float* __restrict__ be, const float* __restrict__ ge,
    const float* __restrict__ bge,
    float* __restrict__ hio,
    float* __restrict__ pm1, float* __restrict__ pm2, int* __restrict__ pma,
    const ushort_t* __restrict__ wL,
    const float* __restrict__ bp,
    const float* __restrict__ gp, const float* __restrict__ bgp,
    const float* __restrict__ b1,
    const float* __restrict__ b2,
    const float* __restrict__ gf, const float* __restrict__ bgf)
{
  int tid = threadIdx.x;
  int d = tid & 127, fourth = tid >> 7;
  int wv = tid >> 6;            // wave 0..7
  int lane = tid & 63;
  int m = lane & 15, q = lane >> 4;
  int t0 = blockIdx.x * TPB;
  int b = t0 >> 8;
  int blk = (t0 >> 3) & (BPL-1);
  int n0a = wv*16;

  const ushort_t* wAb = wL;
  const ushort_t* wBb = wL + WPSZ;
  const ushort_t* wCb = wL + WPSZ + W1SZ;

  __shared__ float    hcur[8*128];    // 4K  h input for own 8 tokens
  __shared__ ushort_t catb[16*256];   // 8K  bf16 A-operand, stage A (swz)
  __shared__ float    sA[16*128];     // 8K  f32 GEMM out (A, then C)
  __shared__ ushort_t h1b[16*128];    // 4K  bf16 A-operand, stage B (swz)
  __shared__ float    h1f[8*128];     // 4K  f32 h1 (stage-C residual)
  __shared__ ushort_t ub[16*512];     // 16K bf16 A-operand, stage C (swz)
  __shared__ float fm1[128], fm2[128];
  __shared__ int   fam[128];
  __shared__ float sm1[4][128], sm2[4][128];
  __shared__ int   sam[4][128];
  __shared__ float xs[512];
  __shared__ float red9[2][12];
  __shared__ float stats[12];

  if (layer == 0){
    // ---- stage x for the whole batch (256 tokens x 2) ----
    xs[tid] = x[(size_t)b*512 + tid];
    // ---- 9 reduction scalars of (We,be) over d ----
    float a = We[d], bw = We[128+d], c = be[d];
    if (fourth == 0){
      float r0=a, r1=bw;        waveRed2(r0,r1);
      float r2=c, r3=a*a;       waveRed2(r2,r3);
      float r4=bw*bw, r5=c*c;   waveRed2(r4,r5);
      float r6=a*bw, r7=a*c;    waveRed2(r6,r7);
      float r8=bw*c, r9=0.f;    waveRed2(r8,r9);
      int w = (tid >> 6) & 1;
      if (lane == 0){
        red9[w][0]=r0; red9[w][1]=r1; red9[w][2]=r2; red9[w][3]=r3;
        red9[w][4]=r4; red9[w][5]=r5; red9[w][6]=r6; red9[w][7]=r7;
        red9[w][8]=r8;
      }
    }
    __syncthreads();
    if (tid < 9) stats[tid] = (red9[0][tid] + red9[1][tid]) * (1.f/128);
    __syncthreads();
    float mA=stats[0], mB=stats[1], mC=stats[2];
    float SAA=stats[3], SBB=stats[4], SCC=stats[5];
    float SAB=stats[6], SAC=stats[7], SBC=stats[8];
    float gev = ge[d], bgev = bge[d];
    // ---- full-batch pool scan: fourth f covers tokens f*64..f*64+63 ----
    float m1=-3.4e38f, m2=-3.4e38f; int am=0;
    for (int i=0;i<64;++i){
      int n = fourth*64 + i;
      float x0 = xs[2*n], x1 = xs[2*n+1];
      float v    = fmaf(x0, a,  fmaf(x1, bw, c));
      float mean = fmaf(x0, mA, fmaf(x1, mB, mC));
      float ev2  = x0*x0*SAA + x1*x1*SBB + SCC
                 + 2.f*(x0*x1*SAB + x0*SAC + x1*SBC);
      float var = ev2 - mean*mean;
      float hv = (v-mean)*rsqrtf(var+EPSV)*gev + bgev;
      poolMerge(m1,m2,am, hv, -3.4e38f, n);
    }
    sm1[fourth][d]=m1; sm2[fourth][d]=m2; sam[fourth][d]=am;
    // ---- own 8 tokens' h ----
    #pragma unroll
    for (int rep=0; rep<2; ++rep){
      int t = fourth*2 + rep;
      int n = (t0 & 255) + t;
      float x0 = xs[2*n], x1 = xs[2*n+1];
      float v    = fmaf(x0, a,  fmaf(x1, bw, c));
      float mean = fmaf(x0, mA, fmaf(x1, mB, mC));
      float ev2  = x0*x0*SAA + x1*x1*SBB + SCC
                 + 2.f*(x0*x1*SAB + x0*SAC + x1*SBC);
      float var = ev2 - mean*mean;
      hcur[t*128 + d] = (v-mean)*rsqrtf(var+EPSV)*gev + bgev;
    }
    __syncthreads();
  } else {
    // ---- merge the batch's 32 layer-0 pool partials (8 per fourth) ----
    {
      size_t base = ((size_t)b*BPL + fourth*8)*128 + d;
      float m1 = pm1[base], m2 = pm2[base]; int am = pma[base];
      #pragma unroll
      for (int i=1;i<8;++i)
        poolMerge(m1,m2,am, pm1[base+(size_t)i*128], pm2[base+(size_t)i*128],
                  pma[base+(size_t)i*128]);
      sm1[fourth][d]=m1; sm2[fourth][d]=m2; sam[fourth][d]=am;
    }
    // ---- own 8 tokens' h0 from hio ----
    #pragma unroll
    for (int rep=0; rep<2; ++rep){
      int t = fourth*2 + rep;
      hcur[t*128 + d] = hio[(size_t)(t0+t)*DD + d];
    }
    __syncthreads();
  }

  if (fourth==0){
    float m1=sm1[0][d], m2=sm2[0][d]; int am=sam[0][d];
    #pragma unroll
    for (int p=1;p<4;++p) poolMerge(m1,m2,am, sm1[p][d], sm2[p][d], sam[p][d]);
    fm1[d]=m1; fm2[d]=m2; fam[d]=am;
  }
  __syncthreads();

  // ---- cat build: catb[8][256] bf16 from hcur + pooled (swizzled) ----
  #pragma unroll
  for (int rep=0; rep<4; ++rep){
    int e = rep*512 + tid;
    int t = e >> 8, cc = e & 255;
    int n = (t0 & 255) + t;
    float v;
    if (cc < DD) v = hcur[t*128 + cc];
    else { int c2 = cc - DD; v = (n==fam[c2]) ? fm2[c2] : fm1[c2]; }
    *(ushort_t*)((char*)catb + ((e*2) ^ ((t&7)<<4))) = f2b(v);
  }
  __syncthreads();

  // ---- stage A: [16x128] = cat[16x256] @ Wp ----
  {
    f32x4 acc = {0.f,0.f,0.f,0.f};
    const char* apb = (const char*)catb;
    int abase = (m*256 + q*8)*2;
    int sw = (m&7)<<4;
    #pragma unroll
    for (int ks=0; ks<8; ++ks){
      bf16x8 wf = *(const bf16x8*)(wAb + ((size_t)(wv*8+ks)*64 + lane)*8);
      bf16x8 af = *(const bf16x8*)(apb + ((abase + ks*64) ^ sw));
      acc = __builtin_amdgcn_mfma_f32_16x16x32_bf16(af, wf, acc, 0,0,0);
    }
    #pragma unroll
    for (int r=0;r<4;++r) sA[(q*4+r)*128 + n0a + m] = acc[r];
  }
  __syncthreads();

  // ---- LN-A: wave t = token t; lane handles d = 2g, 2g+1 ----
  {
    int t = wv, g = lane;
    float2 v2 = *(const float2*)&sA[t*128 + 2*g];
    float v0 = v2.x + bp[2*g]   + hcur[t*128 + 2*g];
    float v1 = v2.y + bp[2*g+1] + hcur[t*128 + 2*g + 1];
    float s = v0+v1, qq = v0*v0 + v1*v1;
    waveRed2(s,qq);
    float mean = s*(1.f/128), var = qq*(1.f/128) - mean*mean;
    float rs = rsqrtf(var + EPSV);
    float o0 = (v0-mean)*rs*gp[2*g]   + bgp[2*g];
    float o1 = (v1-mean)*rs*gp[2*g+1] + bgp[2*g+1];
    unsigned pk = (unsigned)f2b(o0) | ((unsigned)f2b(o1) << 16);
    *(unsigned*)((char*)h1b + (((t*128 + 2*g)*2) ^ ((t&7)<<4))) = pk;
    *(float2*)&h1f[t*128 + 2*g] = make_float2(o0, o1);
  }
  __syncthreads();

  // ---- stage B: [16x512] = h1[16x128] @ W1 ----
  {
    const char* apb = (const char*)h1b;
    int abase = (m*128 + q*8)*2;
    int sw = (m&7)<<4;
    bf16x8 af[4];
    #pragma unroll
    for (int ks=0; ks<4; ++ks)
      af[ks] = *(const bf16x8*)(apb + ((abase + ks*64) ^ sw));
    #pragma unroll
    for (int half=0; half<2; ++half){
      #pragma unroll
      for (int i=0;i<2;++i){
        int n0 = (half*2+i)*128 + wv*16;
        int n0t = (half*2+i)*8 + wv;
        f32x4 acc = {0.f,0.f,0.f,0.f};
        #pragma unroll
        for (int ks=0; ks<4; ++ks){
          bf16x8 wf = *(const bf16x8*)(wBb + ((size_t)(n0t*4+ks)*64 + lane)*8);
          acc = __builtin_amdgcn_mfma_f32_16x16x32_bf16(af[ks], wf, acc, 0,0,0);
        }
        float bb = b1[n0+m];
        #pragma unroll
        for (int r=0;r<4;++r){
          int row = q*4+r;
          *(ushort_t*)((char*)ub + (((row*512 + n0 + m)*2) ^ ((row&7)<<4)))
              = f2b(fmaxf(acc[r] + bb, 0.f));
        }
      }
    }
  }
  __syncthreads();

  // ---- stage C: [16x128] = u[16x512] @ W2 ----
  {
    f32x4 acc = {0.f,0.f,0.f,0.f};
    const char* apb = (const char*)ub;
    int abase = (m*512 + q*8)*2;
    int sw = (m&7)<<4;
    #pragma unroll
    for (int kk=0; kk<16; ++kk){
      bf16x8 wf = *(const bf16x8*)(wCb + ((size_t)(wv*16+kk)*64 + lane)*8);
      bf16x8 af = *(const bf16x8*)(apb + ((abase + kk*64) ^ sw));
      acc = __builtin_amdgcn_mfma_f32_16x16x32_bf16(af, wf, acc, 0,0,0);
    }
    #pragma unroll
    for (int r=0;r<4;++r) sA[(q*4+r)*128 + n0a + m] = acc[r];
  }
  __syncthreads();

  // ---- LN-C: residual h1f -> hio (+ hcur for pool partial) ----
  {
    int t = wv, g = lane;
    float2 v2 = *(const float2*)&sA[t*128 + 2*g];
    float v0 = v2.x + b2[2*g]   + h1f[t*128 + 2*g];
    float v1 = v2.y + b2[2*g+1] + h1f[t*128 + 2*g + 1];
    float s = v0+v1, qq = v0*v0 + v1*v1;
    waveRed2(s,qq);
    float mean = s*(1.f/128), var = qq*(1.f/128) - mean*mean;
    float rs = rsqrtf(var + EPSV);
    float o0 = (v0-mean)*rs*gf[2*g]   + bgf[2*g];
    float o1 = (v1-mean)*rs*gf[2*g+1] + bgf[2*g+1];
    *(float2*)&hio[(size_t)(t0+t)*DD + 2*g] = make_float2(o0, o1);
    *(float2*)&hcur[t*128 + 2*g] = make_float2(o0, o1);
  }
  if (layer == 0){
    __syncthreads();
    if (tid < 128){
      int n0 = t0 & 255;
      float m1 = hcur[tid], m2 = -3.4e38f; int am = n0;
      #pragma unroll
      for (int p=1;p<TPB;++p)
        poolMerge(m1,m2,am, hcur[p*128+tid], -3.4e38f, n0+p);
      size_t idx = ((size_t)b*BPL + blk)*128 + tid;
      pm1[idx]=m1; pm2[idx]=m2; pma[idx]=am;
    }
  }
}

extern "C" void kernel_launch(void* const* d_in, const int* in_sizes, int n_in,
                              void* d_out, int out_size, void* d_ws, size_t ws_size,
                              hipStream_t stream)
{
  const float* x   = (const float*)d_in[0];
  const float* We  = (const float*)d_in[1];
  const float* be  = (const float*)d_in[2];
  const float* ge  = (const float*)d_in[3];
  const float* bge = (const float*)d_in[4];
  const float* Wp  = (const float*)d_in[5];
  const float* bp  = (const float*)d_in[6];
  const float* gp  = (const float*)d_in[7];
  const float* bgp = (const float*)d_in[8];
  const float* W1  = (const float*)d_in[9];
  const float* b1  = (const float*)d_in[10];
  const float* W2  = (const float*)d_in[11];
  const float* b2  = (const float*)d_in[12];
  const float* gf  = (const float*)d_in[13];
  const float* bgf = (const float*)d_in[14];

  float* hio = (float*)d_out;
  char* ws = (char*)d_ws;
  const size_t NP = (size_t)BB*BPL*128;     // 32768
  float* p1 = (float*)ws;            ws += NP*4;
  float* p2 = (float*)ws;            ws += NP*4;
  int*   pa = (int*)ws;              ws += NP*4;
  ushort_t* wcvt = (ushort_t*)ws;

  const int grid = (BB*NN)/TPB;   // 256

  k_prep<<<80, 512, 0, stream>>>(Wp, W1, W2, wcvt);

  k_net<<<grid, 512, 0, stream>>>(0, x, We, be, ge, bge, hio, p1, p2, pa,
      wcvt,
      bp,      gp,      bgp,
      b1,      b2,
      gf,      bgf);

  k_net<<<grid, 512, 0, stream>>>(1, x, We, be, ge, bge, hio, p1, p2, pa,
      wcvt + LAYSZ,
      bp + DD, gp + DD, bgp + DD,
      b1 + HH, b2 + DD,
      gf + DD, bgf + DD);
}

// Round 3
// 103.567 us; speedup vs baseline: 1.8800x; 1.0463x over previous
//
#include <hip/hip_runtime.h>
#include <hip/hip_bf16.h>

#define BB 8
#define NN 256
#define DD 128
#define HH 512
#define LL 2
#define EPSV 1e-5f
#define TPB 8            // tokens per block
#define BPL (NN/TPB)     // pool partials per batch = 32

typedef unsigned short ushort_t;
typedef __attribute__((ext_vector_type(8))) short bf16x8;
typedef __attribute__((ext_vector_type(4))) float f32x4;

// converted-weight segment sizes (bf16 elements)
#define WPSZ (256*128)           // 32768
#define W1SZ (128*512)           // 65536
#define W2SZ (512*128)           // 65536
#define LAYSZ (WPSZ+W1SZ+W2SZ)   // 163840
#define TOTW (2*LAYSZ)           // 327680

#if defined(__has_builtin)
#if __has_builtin(__builtin_amdgcn_sched_barrier)
#define SCHED_FENCE() __builtin_amdgcn_sched_barrier(0)
#endif
#endif
#ifndef SCHED_FENCE
#define SCHED_FENCE()
#endif

__device__ __forceinline__ ushort_t f2b(float v){
  __hip_bfloat16 h = __float2bfloat16(v);
  return *(ushort_t*)&h;
}

__device__ __forceinline__ void waveRed2(float &a, float &b){
  #pragma unroll
  for (int off=32; off>=1; off>>=1){
    a += __shfl_xor(a, off, 64);
    b += __shfl_xor(b, off, 64);
  }
}

__device__ __forceinline__ void poolMerge(float &m1, float &m2, int &am,
                                          float o1, float o2, int oa){
  if (o1 > m1){ m2 = fmaxf(m1, o2); m1 = o1; am = oa; }
  else        { m2 = fmaxf(m2, o1); }
}

// One-time weight conversion: f32 [K][N] -> bf16 fragment-ordered records.
// Record layout (per GEMM tile): element off = rec*512 + lane*8 + j holds
// W[ks*32 + (lane>>4)*8 + j][n0tile*16 + (lane&15)], rec = n0tile*(K/32)+ks.
__global__ __launch_bounds__(512) void k_prep(
    const float* __restrict__ Wp, const float* __restrict__ W1,
    const float* __restrict__ W2, ushort_t* __restrict__ wcvt)
{
  int e8 = blockIdx.x*512 + threadIdx.x;     // chunk index, 40960 total
  if (e8 >= TOTW/8) return;
  int e = e8*8;
  int l2 = (e >= LAYSZ) ? 1 : 0;
  int el = e - l2*LAYSZ;
  const float* src; int N, KSlog, off;
  if (el < WPSZ)           { src = Wp + (size_t)l2*WPSZ; N = 128; KSlog = 3; off = el; }
  else if (el < WPSZ+W1SZ) { src = W1 + (size_t)l2*W1SZ; N = 512; KSlog = 2; off = el - WPSZ; }
  else                     { src = W2 + (size_t)l2*W2SZ; N = 128; KSlog = 4; off = el - (WPSZ+W1SZ); }
  int rec  = off >> 9;
  int ln   = (off >> 3) & 63;
  int n0t  = rec >> KSlog;
  int ks   = rec & ((1<<KSlog)-1);
  int row0 = ks*32 + ((ln>>4)<<3);
  int col  = (n0t<<4) + (ln&15);
  bf16x8 v;
  #pragma unroll
  for (int j=0;j<8;++j) v[j] = (short)f2b(src[(size_t)(row0+j)*N + col]);
  *(bf16x8*)(wcvt + e) = v;
}

// One kernel per layer, 256 blocks x 512 threads (1 block/CU, latency-bound
// serial chain). Round-3 changes vs round-2:
//  * weight fragments for stages A+B prefetched into registers at kernel
//    top (stage C prefetched after stage-A MFMAs) -> VMEM latency hidden
//    under the embed/pool phase instead of exposed after each barrier.
//  * per-token LN stats (mean, rsqrt) precomputed once into an LDS float4
//    table -> 64-iter pool scan drops from ~20 VALU (incl. rsqrt) to ~9
//    VALU + 1 broadcast ds_read_b128 per iteration.
//  * bf16 h-half of catb written during embed/load -> cat phase builds
//    only the pooled half.
__global__ __launch_bounds__(512, 2) void k_net(
    int layer,
    const float* __restrict__ x, const float* __restrict__ We,
    const float* __restrict__ be, const float* __restrict__ ge,
    const float* __restrict__ bge,
    float* __restrict__ hio,
    float* __restrict__ pm1, float* __restrict__ pm2, int* __restrict__ pma,
    const ushort_t* __restrict__ wL,
    const float* __restrict__ bp,
    const float* __restrict__ gp, const float* __restrict__ bgp,
    const float* __restrict__ b1,
    const float* __restrict__ b2,
    const float* __restrict__ gf, const float* __restrict__ bgf)
{
  int tid = threadIdx.x;
  int d = tid & 127, fourth = tid >> 7;
  int wv = tid >> 6;            // wave 0..7
  int lane = tid & 63;
  int m = lane & 15, q = lane >> 4;
  int t0 = blockIdx.x * TPB;
  int b = t0 >> 8;
  int blk = (t0 >> 3) & (BPL-1);
  int n0a = wv*16;

  const ushort_t* wAb = wL;
  const ushort_t* wBb = wL + WPSZ;
  const ushort_t* wCb = wL + WPSZ + W1SZ;

  // ---- prefetch stage-A and stage-B weight fragments (96 VGPRs) ----
  bf16x8 wfa[8], wfb[16];
  #pragma unroll
  for (int ks=0; ks<8; ++ks)
    wfa[ks] = *(const bf16x8*)(wAb + ((size_t)(wv*8+ks)*64 + lane)*8);
  #pragma unroll
  for (int r=0; r<16; ++r)
    wfb[r] = *(const bf16x8*)(wBb + ((size_t)(((r>>2)*8+wv)*4 + (r&3))*64 + lane)*8);
  SCHED_FENCE();

  __shared__ float    hcur[8*128];    // 4K  h input for own 8 tokens (f32)
  __shared__ ushort_t catb[16*256];   // 8K  bf16 A-operand, stage A (swz)
  __shared__ float    sA[16*128];     // 8K  f32 GEMM out (A, then C)
  __shared__ ushort_t h1b[16*128];    // 4K  bf16 A-operand, stage B (swz)
  __shared__ float    h1f[8*128];     // 4K  f32 h1 (stage-C residual)
  __shared__ ushort_t ub[16*512];     // 16K bf16 A-operand, stage C (swz)
  __shared__ float fm1[128], fm2[128];
  __shared__ int   fam[128];
  __shared__ float sm1[4][128], sm2[4][128];
  __shared__ int   sam[4][128];
  __shared__ float xs[512];
  __shared__ float red9[2][12];
  __shared__ float stats[12];
  __shared__ float4 tk[256];          // 4K  per-token (x0, x1, mean, rs)

  if (layer == 0){
    // ---- stage x for the whole batch (256 tokens x 2) ----
    xs[tid] = x[(size_t)b*512 + tid];
    // ---- 9 reduction scalars of (We,be) over d ----
    float a = We[d], bw = We[128+d], c = be[d];
    if (fourth == 0){
      float r0=a, r1=bw;        waveRed2(r0,r1);
      float r2=c, r3=a*a;       waveRed2(r2,r3);
      float r4=bw*bw, r5=c*c;   waveRed2(r4,r5);
      float r6=a*bw, r7=a*c;    waveRed2(r6,r7);
      float r8=bw*c, r9=0.f;    waveRed2(r8,r9);
      int w = (tid >> 6) & 1;
      if (lane == 0){
        red9[w][0]=r0; red9[w][1]=r1; red9[w][2]=r2; red9[w][3]=r3;
        red9[w][4]=r4; red9[w][5]=r5; red9[w][6]=r6; red9[w][7]=r7;
        red9[w][8]=r8;
      }
    }
    __syncthreads();
    if (tid < 9) stats[tid] = (red9[0][tid] + red9[1][tid]) * (1.f/128);
    __syncthreads();
    // ---- per-token LN stats: one thread per token, fully parallel ----
    if (tid < 256){
      float mA=stats[0], mB=stats[1], mC=stats[2];
      float SAA=stats[3], SBB=stats[4], SCC=stats[5];
      float SAB=stats[6], SAC=stats[7], SBC=stats[8];
      float x0 = xs[2*tid], x1 = xs[2*tid+1];
      float mean = fmaf(x0, mA, fmaf(x1, mB, mC));
      float ev2  = x0*x0*SAA + x1*x1*SBB + SCC
                 + 2.f*(x0*x1*SAB + x0*SAC + x1*SBC);
      float var = ev2 - mean*mean;
      tk[tid] = make_float4(x0, x1, mean, rsqrtf(var + EPSV));
    }
    __syncthreads();
    float gev = ge[d], bgev = bge[d];
    // ---- full-batch pool scan: fourth f covers tokens f*64..f*64+63 ----
    float m1=-3.4e38f, m2=-3.4e38f; int am=0;
    for (int i=0;i<64;++i){
      int n = fourth*64 + i;
      float4 t4 = tk[n];                       // broadcast ds_read_b128
      float v  = fmaf(t4.x, a, fmaf(t4.y, bw, c));
      float hv = fmaf((v - t4.z)*t4.w, gev, bgev);
      poolMerge(m1,m2,am, hv, -3.4e38f, n);
    }
    sm1[fourth][d]=m1; sm2[fourth][d]=m2; sam[fourth][d]=am;
    // ---- own 8 tokens' h (f32 + bf16 h-half of catb) ----
    #pragma unroll
    for (int rep=0; rep<2; ++rep){
      int t = fourth*2 + rep;
      int n = (t0 & 255) + t;
      float4 t4 = tk[n];
      float v  = fmaf(t4.x, a, fmaf(t4.y, bw, c));
      float hv = fmaf((v - t4.z)*t4.w, gev, bgev);
      hcur[t*128 + d] = hv;
      *(ushort_t*)((char*)catb + (((t*256 + d)*2) ^ ((t&7)<<4))) = f2b(hv);
    }
    __syncthreads();
  } else {
    // ---- merge the batch's 32 layer-0 pool partials (8 per fourth) ----
    {
      size_t base = ((size_t)b*BPL + fourth*8)*128 + d;
      float m1 = pm1[base], m2 = pm2[base]; int am = pma[base];
      #pragma unroll
      for (int i=1;i<8;++i)
        poolMerge(m1,m2,am, pm1[base+(size_t)i*128], pm2[base+(size_t)i*128],
                  pma[base+(size_t)i*128]);
      sm1[fourth][d]=m1; sm2[fourth][d]=m2; sam[fourth][d]=am;
    }
    // ---- own 8 tokens' h0 from hio (f32 + bf16 h-half of catb) ----
    #pragma unroll
    for (int rep=0; rep<2; ++rep){
      int t = fourth*2 + rep;
      float hv = hio[(size_t)(t0+t)*DD + d];
      hcur[t*128 + d] = hv;
      *(ushort_t*)((char*)catb + (((t*256 + d)*2) ^ ((t&7)<<4))) = f2b(hv);
    }
    __syncthreads();
  }

  if (fourth==0){
    float m1=sm1[0][d], m2=sm2[0][d]; int am=sam[0][d];
    #pragma unroll
    for (int p=1;p<4;++p) poolMerge(m1,m2,am, sm1[p][d], sm2[p][d], sam[p][d]);
    fm1[d]=m1; fm2[d]=m2; fam[d]=am;
  }
  __syncthreads();

  // ---- cat build: only the pooled half catb[t][128..255] (swizzled) ----
  #pragma unroll
  for (int rep=0; rep<2; ++rep){
    int e = rep*512 + tid;
    int t = e >> 7, c2 = e & 127;
    int n = (t0 & 255) + t;
    float v = (n==fam[c2]) ? fm2[c2] : fm1[c2];
    *(ushort_t*)((char*)catb + (((t*256 + 128 + c2)*2) ^ ((t&7)<<4))) = f2b(v);
  }
  __syncthreads();

  // ---- stage A: [16x128] = cat[16x256] @ Wp (weights pre-fetched) ----
  {
    f32x4 acc = {0.f,0.f,0.f,0.f};
    const char* apb = (const char*)catb;
    int abase = (m*256 + q*8)*2;
    int sw = (m&7)<<4;
    #pragma unroll
    for (int ks=0; ks<8; ++ks){
      bf16x8 af = *(const bf16x8*)(apb + ((abase + ks*64) ^ sw));
      acc = __builtin_amdgcn_mfma_f32_16x16x32_bf16(af, wfa[ks], acc, 0,0,0);
    }
    #pragma unroll
    for (int r=0;r<4;++r) sA[(q*4+r)*128 + n0a + m] = acc[r];
  }
  // ---- prefetch stage-C weight fragments (wfa now dead) ----
  bf16x8 wfc[16];
  #pragma unroll
  for (int kk=0; kk<16; ++kk)
    wfc[kk] = *(const bf16x8*)(wCb + ((size_t)(wv*16+kk)*64 + lane)*8);
  SCHED_FENCE();
  __syncthreads();

  // ---- LN-A: wave t = token t; lane handles d = 2g, 2g+1 ----
  {
    int t = wv, g = lane;
    float2 v2 = *(const float2*)&sA[t*128 + 2*g];
    float v0 = v2.x + bp[2*g]   + hcur[t*128 + 2*g];
    float v1 = v2.y + bp[2*g+1] + hcur[t*128 + 2*g + 1];
    float s = v0+v1, qq = v0*v0 + v1*v1;
    waveRed2(s,qq);
    float mean = s*(1.f/128), var = qq*(1.f/128) - mean*mean;
    float rs = rsqrtf(var + EPSV);
    float o0 = (v0-mean)*rs*gp[2*g]   + bgp[2*g];
    float o1 = (v1-mean)*rs*gp[2*g+1] + bgp[2*g+1];
    unsigned pk = (unsigned)f2b(o0) | ((unsigned)f2b(o1) << 16);
    *(unsigned*)((char*)h1b + (((t*128 + 2*g)*2) ^ ((t&7)<<4))) = pk;
    *(float2*)&h1f[t*128 + 2*g] = make_float2(o0, o1);
  }
  __syncthreads();

  // ---- stage B: [16x512] = h1[16x128] @ W1 (weights pre-fetched) ----
  {
    const char* apb = (const char*)h1b;
    int abase = (m*128 + q*8)*2;
    int sw = (m&7)<<4;
    bf16x8 af[4];
    #pragma unroll
    for (int ks=0; ks<4; ++ks)
      af[ks] = *(const bf16x8*)(apb + ((abase + ks*64) ^ sw));
    #pragma unroll
    for (int half=0; half<2; ++half){
      #pragma unroll
      for (int i=0;i<2;++i){
        int idx4 = half*2+i;
        int n0 = idx4*128 + wv*16;
        f32x4 acc = {0.f,0.f,0.f,0.f};
        #pragma unroll
        for (int ks=0; ks<4; ++ks)
          acc = __builtin_amdgcn_mfma_f32_16x16x32_bf16(af[ks], wfb[idx4*4+ks], acc, 0,0,0);
        float bb = b1[n0+m];
        #pragma unroll
        for (int r=0;r<4;++r){
          int row = q*4+r;
          *(ushort_t*)((char*)ub + (((row*512 + n0 + m)*2) ^ ((row&7)<<4)))
              = f2b(fmaxf(acc[r] + bb, 0.f));
        }
      }
    }
  }
  __syncthreads();

  // ---- stage C: [16x128] = u[16x512] @ W2 (weights pre-fetched) ----
  {
    f32x4 acc = {0.f,0.f,0.f,0.f};
    const char* apb = (const char*)ub;
    int abase = (m*512 + q*8)*2;
    int sw = (m&7)<<4;
    #pragma unroll
    for (int kk=0; kk<16; ++kk){
      bf16x8 af = *(const bf16x8*)(apb + ((abase + kk*64) ^ sw));
      acc = __builtin_amdgcn_mfma_f32_16x16x32_bf16(af, wfc[kk], acc, 0,0,0);
    }
    #pragma unroll
    for (int r=0;r<4;++r) sA[(q*4+r)*128 + n0a + m] = acc[r];
  }
  __syncthreads();

  // ---- LN-C: residual h1f -> hio (+ hcur for pool partial) ----
  {
    int t = wv, g = lane;
    float2 v2 = *(const float2*)&sA[t*128 + 2*g];
    float v0 = v2.x + b2[2*g]   + h1f[t*128 + 2*g];
    float v1 = v2.y + b2[2*g+1] + h1f[t*128 + 2*g + 1];
    float s = v0+v1, qq = v0*v0 + v1*v1;
    waveRed2(s,qq);
    float mean = s*(1.f/128), var = qq*(1.f/128) - mean*mean;
    float rs = rsqrtf(var + EPSV);
    float o0 = (v0-mean)*rs*gf[2*g]   + bgf[2*g];
    float o1 = (v1-mean)*rs*gf[2*g+1] + bgf[2*g+1];
    *(float2*)&hio[(size_t)(t0+t)*DD + 2*g] = make_float2(o0, o1);
    *(float2*)&hcur[t*128 + 2*g] = make_float2(o0, o1);
  }
  if (layer == 0){
    __syncthreads();
    if (tid < 128){
      int n0 = t0 & 255;
      float m1 = hcur[tid], m2 = -3.4e38f; int am = n0;
      #pragma unroll
      for (int p=1;p<TPB;++p)
        poolMerge(m1,m2,am, hcur[p*128+tid], -3.4e38f, n0+p);
      size_t idx = ((size_t)b*BPL + blk)*128 + tid;
      pm1[idx]=m1; pm2[idx]=m2; pma[idx]=am;
    }
  }
}

extern "C" void kernel_launch(void* const* d_in, const int* in_sizes, int n_in,
                              void* d_out, int out_size, void* d_ws, size_t ws_size,
                              hipStream_t stream)
{
  const float* x   = (const float*)d_in[0];
  const float* We  = (const float*)d_in[1];
  const float* be  = (const float*)d_in[2];
  const float* ge  = (const float*)d_in[3];
  const float* bge = (const float*)d_in[4];
  const float* Wp  = (const float*)d_in[5];
  const float* bp  = (const float*)d_in[6];
  const float* gp  = (const float*)d_in[7];
  const float* bgp = (const float*)d_in[8];
  const float* W1  = (const float*)d_in[9];
  const float* b1  = (const float*)d_in[10];
  const float* W2  = (const float*)d_in[11];
  const float* b2  = (const float*)d_in[12];
  const float* gf  = (const float*)d_in[13];
  const float* bgf = (const float*)d_in[14];

  float* hio = (float*)d_out;
  char* ws = (char*)d_ws;
  const size_t NP = (size_t)BB*BPL*128;     // 32768
  float* p1 = (float*)ws;            ws += NP*4;
  float* p2 = (float*)ws;            ws += NP*4;
  int*   pa = (int*)ws;              ws += NP*4;
  ushort_t* wcvt = (ushort_t*)ws;

  const int grid = (BB*NN)/TPB;   // 256

  k_prep<<<80, 512, 0, stream>>>(Wp, W1, W2, wcvt);

  k_net<<<grid, 512, 0, stream>>>(0, x, We, be, ge, bge, hio, p1, p2, pa,
      wcvt,
      bp,      gp,      bgp,
      b1,      b2,
      gf,      bgf);

  k_net<<<grid, 512, 0, stream>>>(1, x, We, be, ge, bge, hio, p1, p2, pa,
      wcvt + LAYSZ,
      bp + DD, gp + DD, bgp + DD,
      b1 + HH, b2 + DD,
      gf + DD, bgf + DD);
}